// Round 2
// baseline (149.652 us; speedup 1.0000x reference)
//
#include <hip/hip_runtime.h>
#include <stdint.h>

#define KROWS 8192
#define DDIM  768
#define NUMG  256
#define BM    128
#define BK    64
#define NT    (DDIM / BK)
#define MARGIN_F 0.1f

typedef short bf16x8 __attribute__((ext_vector_type(8)));
typedef float f32x4 __attribute__((ext_vector_type(4)));
typedef unsigned short u16x8 __attribute__((ext_vector_type(8)));

typedef __attribute__((address_space(3))) unsigned char lds_byte;
typedef __attribute__((address_space(1))) const unsigned char glob_byte;

__device__ __forceinline__ uint32_t enc_f32(float f) {
  uint32_t b = __float_as_uint(f);
  return (b & 0x80000000u) ? ~b : (b | 0x80000000u);
}
__device__ __forceinline__ float dec_f32(uint32_t u) {
  uint32_t b = (u & 0x80000000u) ? (u & 0x7FFFFFFFu) : ~u;
  return __uint_as_float(b);
}
__device__ __forceinline__ unsigned short f2bf(float f) {
  uint32_t b = __float_as_uint(f);
  uint32_t r = (b + 0x7FFFu + ((b >> 16) & 1u)) >> 16;
  return (unsigned short)r;
}

// ---------------- init: zero group arrays ----------------
__global__ void init_k(uint32_t* __restrict__ gmin, uint32_t* __restrict__ gmax,
                       int* __restrict__ counts) {
  int t = threadIdx.x;
  gmin[t] = 0xFFFFFFFFu;  // encodes +max
  gmax[t] = 0u;           // encodes -max
  counts[t] = 0;
}

// ---------------- extract group ids + counts ----------------
__global__ void extract_k(const int* __restrict__ pidx, int* __restrict__ gids,
                          int* __restrict__ counts) {
  int t = blockIdx.x * blockDim.x + threadIdx.x;
  if (t < KROWS) {
    int g = pidx[2 * t + 1] & (NUMG - 1);
    gids[t] = g;
    atomicAdd(&counts[g], 1);
  }
}

// ---------------- f32 -> bf16 convert (8 elems/thread) ----------------
__global__ void convert_k(const float* __restrict__ x, unsigned short* __restrict__ xb) {
  int t = blockIdx.x * blockDim.x + threadIdx.x;  // KROWS*DDIM/8 threads
  const float4* p = reinterpret_cast<const float4*>(x + 8 * (size_t)t);
  float4 a = p[0], b = p[1];
  u16x8 r;
  r[0] = f2bf(a.x); r[1] = f2bf(a.y); r[2] = f2bf(a.z); r[3] = f2bf(a.w);
  r[4] = f2bf(b.x); r[5] = f2bf(b.y); r[6] = f2bf(b.z); r[7] = f2bf(b.w);
  *reinterpret_cast<u16x8*>(xb + 8 * (size_t)t) = r;
}

// ---------------- main fused Gram + margin-reduce kernel ----------------
// Lower-triangle tiles only (ib >= jb). 128x128 tile, BK=64, 4 waves (2x2),
// each wave 64x64 = 4x4 fragments of 16x16x32 bf16 MFMA.
// LDS XOR-swizzled (byte ^= (row&7)<<4) via pre-swizzled global source.
// DOUBLE-BUFFERED: stage tile t+1 before computing tile t (T3 2-phase).
__launch_bounds__(256, 2)
__global__ void gram_margin_k(const unsigned short* __restrict__ xb,
                              const int* __restrict__ gids,
                              uint32_t* __restrict__ gmin,
                              uint32_t* __restrict__ gmax) {
  __shared__ unsigned short sA[2][BM * BK];
  __shared__ unsigned short sB[2][BM * BK];
  __shared__ uint32_t lgmin[NUMG];
  __shared__ uint32_t lgmax[NUMG];
  __shared__ int sgr[BM];
  __shared__ int sgc[BM];

  const int tid  = threadIdx.x;
  const int lane = tid & 63;
  const int wid  = tid >> 6;
  const int wr   = wid >> 1, wc = wid & 1;
  const int lr   = lane & 15, lh = lane >> 4;

  // decode triangular block index -> (ib, jb), ib >= jb
  int bid = blockIdx.x;
  int ib = (int)((sqrtf(8.0f * (float)bid + 1.0f) - 1.0f) * 0.5f);
  while ((ib + 1) * (ib + 2) / 2 <= bid) ++ib;
  while (ib * (ib + 1) / 2 > bid) --ib;
  int jb = bid - ib * (ib + 1) / 2;
  const int i0 = ib * BM, j0 = jb * BM;

  if (tid < NUMG) { lgmin[tid] = 0xFFFFFFFFu; lgmax[tid] = 0u; }
  if (tid < BM)   { sgr[tid] = gids[i0 + tid]; sgc[tid] = gids[j0 + tid]; }

  f32x4 acc[4][4];
  const f32x4 zz = {0.f, 0.f, 0.f, 0.f};
#pragma unroll
  for (int m = 0; m < 4; ++m)
#pragma unroll
    for (int n = 0; n < 4; ++n) acc[m][n] = zz;

  const int srow = tid >> 3;   // 0..31 (row within 32-row staging chunk)
  const int schunk = tid & 7;  // 16B chunk within 128B row

  // ---- staging: issue 8 global_load_lds for k-tile kt into buffer buf ----
  auto stage = [&](int buf, int kt) {
    const int k0 = kt * BK;
#pragma unroll
    for (int c = 0; c < 4; ++c) {
      int row = c * 32 + srow;
      int chunk = schunk ^ (row & 7);  // pre-swizzle global source
      const unsigned short* ga = xb + (size_t)(i0 + row) * DDIM + k0 + chunk * 8;
      const unsigned short* gb = xb + (size_t)(j0 + row) * DDIM + k0 + chunk * 8;
      unsigned short* la = sA[buf] + c * 2048 + tid * 8;
      unsigned short* lb = sB[buf] + c * 2048 + tid * 8;
      __builtin_amdgcn_global_load_lds((glob_byte*)ga, (lds_byte*)la, 16, 0, 0);
      __builtin_amdgcn_global_load_lds((glob_byte*)gb, (lds_byte*)lb, 16, 0, 0);
    }
  };

  // ---- compute: 32 MFMAs on buffer buf ----
  auto compute = [&](int buf) {
#pragma unroll
    for (int ks = 0; ks < 2; ++ks) {
      bf16x8 af[4], bfr[4];
#pragma unroll
      for (int m = 0; m < 4; ++m) {
        int row = wr * 64 + m * 16 + lr;
        int byteoff = row * 128 + ((lh * 16 + ks * 64) ^ ((row & 7) << 4));
        af[m] = *reinterpret_cast<const bf16x8*>(
            reinterpret_cast<const char*>(sA[buf]) + byteoff);
      }
#pragma unroll
      for (int n = 0; n < 4; ++n) {
        int row = wc * 64 + n * 16 + lr;
        int byteoff = row * 128 + ((lh * 16 + ks * 64) ^ ((row & 7) << 4));
        bfr[n] = *reinterpret_cast<const bf16x8*>(
            reinterpret_cast<const char*>(sB[buf]) + byteoff);
      }
#pragma unroll
      for (int m = 0; m < 4; ++m)
#pragma unroll
        for (int n = 0; n < 4; ++n)
          acc[m][n] = __builtin_amdgcn_mfma_f32_16x16x32_bf16(af[m], bfr[n],
                                                              acc[m][n], 0, 0, 0);
    }
  };

  // ---- 2-phase double-buffered K loop ----
  stage(0, 0);
  __syncthreads();  // drains vmcnt(0): buf0 ready; also covers lgmin/sgr init
  int cur = 0;
  for (int kt = 0; kt < NT - 1; ++kt) {
    stage(cur ^ 1, kt + 1);  // issue next tile's loads (latency hides under compute)
    compute(cur);
    __syncthreads();         // drains vmcnt(0): buf^1 ready; buf reusable
    cur ^= 1;
  }
  compute(cur);

  // ---------------- fused epilogue ----------------
  // C/D layout: col = lane&15, row = (lane>>4)*4 + reg  [m89-verified]
  int gi[4][4];
#pragma unroll
  for (int m = 0; m < 4; ++m)
#pragma unroll
    for (int r = 0; r < 4; ++r) gi[m][r] = sgr[wr * 64 + m * 16 + lh * 4 + r];
  int gj[4];
#pragma unroll
  for (int n = 0; n < 4; ++n) gj[n] = sgc[wc * 64 + n * 16 + lr];

  float rmin[4][4], rmax[4][4], cmax[4];
#pragma unroll
  for (int m = 0; m < 4; ++m)
#pragma unroll
    for (int r = 0; r < 4; ++r) { rmin[m][r] = 3.0e38f; rmax[m][r] = -3.0e38f; }
#pragma unroll
  for (int n = 0; n < 4; ++n) cmax[n] = -3.0e38f;

  const bool offdiag = (ib != jb);
#pragma unroll
  for (int m = 0; m < 4; ++m) {
#pragma unroll
    for (int r = 0; r < 4; ++r) {
      int ii = i0 + wr * 64 + m * 16 + lh * 4 + r;
#pragma unroll
      for (int n = 0; n < 4; ++n) {
        int jj = j0 + wc * 64 + n * 16 + lr;
        float s = acc[m][n][r];
        if (offdiag || (ii > jj)) {
          if (gi[m][r] == gj[n]) {
            rmin[m][r] = fminf(rmin[m][r], s);
          } else {
            rmax[m][r] = fmaxf(rmax[m][r], s);
            cmax[n] = fmaxf(cmax[n], s);
          }
        }
      }
    }
  }

  // reduce rows across the 16 j-lanes (xor 1,2,4,8)
#pragma unroll
  for (int s = 1; s <= 8; s <<= 1) {
#pragma unroll
    for (int m = 0; m < 4; ++m)
#pragma unroll
      for (int r = 0; r < 4; ++r) {
        rmin[m][r] = fminf(rmin[m][r], __shfl_xor(rmin[m][r], s, 64));
        rmax[m][r] = fmaxf(rmax[m][r], __shfl_xor(rmax[m][r], s, 64));
      }
  }
  // reduce cols across the 4 i-lane-groups (xor 16, 32)
#pragma unroll
  for (int s = 16; s <= 32; s <<= 1)
#pragma unroll
    for (int n = 0; n < 4; ++n)
      cmax[n] = fmaxf(cmax[n], __shfl_xor(cmax[n], s, 64));

  if (lr == 0) {
#pragma unroll
    for (int m = 0; m < 4; ++m)
#pragma unroll
      for (int r = 0; r < 4; ++r) {
        if (rmin[m][r] < 1.0e38f) atomicMin(&lgmin[gi[m][r]], enc_f32(rmin[m][r]));
        if (rmax[m][r] > -1.0e38f) atomicMax(&lgmax[gi[m][r]], enc_f32(rmax[m][r]));
      }
  }
  if (lh == 0) {
#pragma unroll
    for (int n = 0; n < 4; ++n)
      if (cmax[n] > -1.0e38f) atomicMax(&lgmax[gj[n]], enc_f32(cmax[n]));
  }
  __syncthreads();

  // merge block-local group arrays to global (tid covers all 256 groups)
  {
    uint32_t mn = lgmin[tid], mx = lgmax[tid];
    if (mn != 0xFFFFFFFFu) atomicMin(&gmin[tid], mn);
    if (mx != 0u) atomicMax(&gmax[tid], mx);
  }
}

// ---------------- finalize: per-group margin + mean ----------------
__global__ void finalize_k(const uint32_t* __restrict__ gmin,
                           const uint32_t* __restrict__ gmax,
                           const int* __restrict__ counts,
                           float* __restrict__ out) {
  __shared__ float s_num[256];
  __shared__ float s_den[256];
  int t = threadIdx.x;
  float per = 0.f, ne = 0.f;
  if (counts[t] > 0) {
    ne = 1.f;
    float mn = (gmin[t] == 0xFFFFFFFFu) ? 1.0e9f : dec_f32(gmin[t]);
    float mx = (gmax[t] == 0u) ? -1.0e9f : dec_f32(gmax[t]);
    per = fmaxf(0.0f, mx - mn + MARGIN_F);
  }
  s_num[t] = per;
  s_den[t] = ne;
  __syncthreads();
  for (int s = 128; s > 0; s >>= 1) {
    if (t < s) { s_num[t] += s_num[t + s]; s_den[t] += s_den[t + s]; }
    __syncthreads();
  }
  if (t == 0) out[0] = s_num[0] / s_den[0];
}

extern "C" void kernel_launch(void* const* d_in, const int* in_sizes, int n_in,
                              void* d_out, int out_size, void* d_ws, size_t ws_size,
                              hipStream_t stream) {
  const float* x   = (const float*)d_in[0];
  const int* pidx  = (const int*)d_in[1];
  float* out       = (float*)d_out;

  char* ws = (char*)d_ws;
  unsigned short* xb = (unsigned short*)ws;
  size_t off = (size_t)KROWS * DDIM * 2;          // 12,582,912 B
  int* gids      = (int*)(ws + off); off += (size_t)KROWS * 4;
  int* counts    = (int*)(ws + off); off += NUMG * 4;
  uint32_t* gmin = (uint32_t*)(ws + off); off += NUMG * 4;
  uint32_t* gmax = (uint32_t*)(ws + off); off += NUMG * 4;

  hipLaunchKernelGGL(init_k, dim3(1), dim3(NUMG), 0, stream, gmin, gmax, counts);
  hipLaunchKernelGGL(extract_k, dim3(KROWS / 256), dim3(256), 0, stream,
                     pidx, gids, counts);
  hipLaunchKernelGGL(convert_k, dim3((KROWS * DDIM / 8) / 256), dim3(256), 0, stream,
                     x, xb);
  const int ntiles = KROWS / BM;                  // 64
  hipLaunchKernelGGL(gram_margin_k, dim3(ntiles * (ntiles + 1) / 2), dim3(256), 0,
                     stream, xb, gids, gmin, gmax);
  hipLaunchKernelGGL(finalize_k, dim3(1), dim3(NUMG), 0, stream,
                     gmin, gmax, counts, out);
}

// Round 3
// 145.720 us; speedup vs baseline: 1.0270x; 1.0270x over previous
//
#include <hip/hip_runtime.h>
#include <stdint.h>

#define KROWS 8192
#define DDIM  768
#define NUMG  256
#define BM    256
#define BK    64
#define NT    (DDIM / BK)     // 12 K-tiles
#define NTILES (KROWS / BM)   // 32 row/col tiles
#define MARGIN_F 0.1f

typedef short bf16x8 __attribute__((ext_vector_type(8)));
typedef float f32x4 __attribute__((ext_vector_type(4)));
typedef unsigned short u16x8 __attribute__((ext_vector_type(8)));

typedef __attribute__((address_space(3))) unsigned char lds_byte;
typedef __attribute__((address_space(1))) const unsigned char glob_byte;

__device__ __forceinline__ uint32_t enc_f32(float f) {
  uint32_t b = __float_as_uint(f);
  return (b & 0x80000000u) ? ~b : (b | 0x80000000u);
}
__device__ __forceinline__ float dec_f32(uint32_t u) {
  uint32_t b = (u & 0x80000000u) ? (u & 0x7FFFFFFFu) : ~u;
  return __uint_as_float(b);
}
__device__ __forceinline__ unsigned short f2bf(float f) {
  uint32_t b = __float_as_uint(f);
  uint32_t r = (b + 0x7FFFu + ((b >> 16) & 1u)) >> 16;
  return (unsigned short)r;
}

// ---------------- init: group arrays ----------------
__global__ void init_k(uint32_t* __restrict__ gmin, uint32_t* __restrict__ gmax,
                       int* __restrict__ counts) {
  int t = threadIdx.x;
  gmin[t] = 0xFFFFFFFFu;
  gmax[t] = 0u;
  counts[t] = 0;
}

// ---------------- extract group ids + counts ----------------
__global__ void extract_k(const int* __restrict__ pidx, int* __restrict__ gids,
                          int* __restrict__ counts) {
  int t = blockIdx.x * blockDim.x + threadIdx.x;
  if (t < KROWS) {
    int g = pidx[2 * t + 1] & (NUMG - 1);
    gids[t] = g;
    atomicAdd(&counts[g], 1);
  }
}

// ---------------- f32 -> bf16 convert ----------------
__global__ void convert_k(const float* __restrict__ x, unsigned short* __restrict__ xb) {
  int t = blockIdx.x * blockDim.x + threadIdx.x;
  const float4* p = reinterpret_cast<const float4*>(x + 8 * (size_t)t);
  float4 a = p[0], b = p[1];
  u16x8 r;
  r[0] = f2bf(a.x); r[1] = f2bf(a.y); r[2] = f2bf(a.z); r[3] = f2bf(a.w);
  r[4] = f2bf(b.x); r[5] = f2bf(b.y); r[6] = f2bf(b.z); r[7] = f2bf(b.w);
  *reinterpret_cast<u16x8*>(xb + 8 * (size_t)t) = r;
}

// ---------------- main fused Gram + margin-reduce kernel ----------------
// 256x256 tile, BK=64, 8 waves (2Mx4N), per-wave 128x64 = 8x4 frags 16x16x32.
// Double-buffered LDS with COUNTED vmcnt (never 0 in main loop) + raw
// s_barrier (no drain). XOR swizzle byte ^= (row&7)<<4 via pre-swizzled src.
__launch_bounds__(512, 2)
__global__ void gram_margin_k(const unsigned short* __restrict__ xb,
                              const int* __restrict__ gids,
                              uint32_t* __restrict__ gmin,
                              uint32_t* __restrict__ gmax) {
  __shared__ unsigned short sA[2][BM * BK];   // 2 x 32 KB
  __shared__ unsigned short sB[2][BM * BK];   // 2 x 32 KB
  __shared__ uint32_t lgmin[NUMG];
  __shared__ uint32_t lgmax[NUMG];
  __shared__ int sgr[BM];
  __shared__ int sgc[BM];

  const int tid  = threadIdx.x;
  const int lane = tid & 63;
  const int wid  = tid >> 6;            // 0..7
  const int wr   = wid >> 2, wc = wid & 3;
  const int lr   = lane & 15, lh = lane >> 4;

  // triangular block decode (ib >= jb), 32x33/2 = 528 blocks
  int bid = blockIdx.x;
  int ib = (int)((sqrtf(8.0f * (float)bid + 1.0f) - 1.0f) * 0.5f);
  while ((ib + 1) * (ib + 2) / 2 <= bid) ++ib;
  while (ib * (ib + 1) / 2 > bid) --ib;
  int jb = bid - ib * (ib + 1) / 2;
  const int i0 = ib * BM, j0 = jb * BM;

  if (tid < NUMG) {
    lgmin[tid] = 0xFFFFFFFFu; lgmax[tid] = 0u;
    sgr[tid] = gids[i0 + tid];
    sgc[tid] = gids[j0 + tid];
  }

  f32x4 acc[8][4];
  const f32x4 zz = {0.f, 0.f, 0.f, 0.f};
#pragma unroll
  for (int m = 0; m < 8; ++m)
#pragma unroll
    for (int n = 0; n < 4; ++n) acc[m][n] = zz;

  // staging: 512 threads, 4 issue-rounds per matrix, 16B each
  const int srow = tid >> 3;    // 0..63
  const int schunk = tid & 7;   // 16B chunk in 128B row

  auto stage = [&](int buf, int kt) {
    const int k0 = kt * BK;
#pragma unroll
    for (int c = 0; c < 4; ++c) {
      int row = c * 64 + srow;
      int chunk = schunk ^ (row & 7);   // pre-swizzled global source
      const unsigned short* ga = xb + (size_t)(i0 + row) * DDIM + k0 + chunk * 8;
      const unsigned short* gb = xb + (size_t)(j0 + row) * DDIM + k0 + chunk * 8;
      unsigned short* la = sA[buf] + (size_t)row * 64 + schunk * 8;
      unsigned short* lb = sB[buf] + (size_t)row * 64 + schunk * 8;
      __builtin_amdgcn_global_load_lds((glob_byte*)ga, (lds_byte*)la, 16, 0, 0);
      __builtin_amdgcn_global_load_lds((glob_byte*)gb, (lds_byte*)lb, 16, 0, 0);
    }
  };

  auto compute = [&](int buf) {
#pragma unroll
    for (int ks = 0; ks < 2; ++ks) {
      bf16x8 af[8], bfr[4];
#pragma unroll
      for (int m = 0; m < 8; ++m) {
        int row = wr * 128 + m * 16 + lr;
        int byteoff = row * 128 + ((lh * 16 + ks * 64) ^ ((row & 7) << 4));
        af[m] = *reinterpret_cast<const bf16x8*>(
            reinterpret_cast<const char*>(sA[buf]) + byteoff);
      }
#pragma unroll
      for (int n = 0; n < 4; ++n) {
        int row = wc * 64 + n * 16 + lr;
        int byteoff = row * 128 + ((lh * 16 + ks * 64) ^ ((row & 7) << 4));
        bfr[n] = *reinterpret_cast<const bf16x8*>(
            reinterpret_cast<const char*>(sB[buf]) + byteoff);
      }
      __builtin_amdgcn_s_setprio(1);
#pragma unroll
      for (int m = 0; m < 8; ++m)
#pragma unroll
        for (int n = 0; n < 4; ++n)
          acc[m][n] = __builtin_amdgcn_mfma_f32_16x16x32_bf16(af[m], bfr[n],
                                                              acc[m][n], 0, 0, 0);
      __builtin_amdgcn_s_setprio(0);
    }
  };

  // ---- prologue: 2 tiles in flight ----
  stage(0, 0);
  stage(1, 1);
  asm volatile("s_waitcnt vmcnt(8) lgkmcnt(0)" ::: "memory");  // tile0 + LDS init done
  __builtin_amdgcn_sched_barrier(0);
  __builtin_amdgcn_s_barrier();

  // ---- main loop: counted vmcnt, loads stay in flight across barriers ----
  int cur = 0;
  for (int kt = 0; kt < NT - 2; ++kt) {
    compute(cur);                        // tile kt (landed)
    __builtin_amdgcn_s_barrier();        // B1: all waves done reading buf[cur]
    stage(cur, kt + 2);                  // refill with tile kt+2 (8 new loads)
    asm volatile("s_waitcnt vmcnt(8)" ::: "memory");  // tile kt+1 landed
    __builtin_amdgcn_sched_barrier(0);
    __builtin_amdgcn_s_barrier();        // B2: everyone sees tile kt+1
    cur ^= 1;
  }
  compute(cur);                          // tile NT-2
  asm volatile("s_waitcnt vmcnt(0)" ::: "memory");    // tile NT-1 landed
  __builtin_amdgcn_sched_barrier(0);
  __builtin_amdgcn_s_barrier();
  compute(cur ^ 1);                      // tile NT-1

  // ---------------- fused epilogue ----------------
  // C/D: col = lane&15, row = (lane>>4)*4 + reg
  int gj[4];
#pragma unroll
  for (int n = 0; n < 4; ++n) gj[n] = sgc[wc * 64 + n * 16 + lr];

  const bool offdiag = (ib != jb);
  float cmax[4];
#pragma unroll
  for (int n = 0; n < 4; ++n) cmax[n] = -3.0e38f;

#pragma unroll
  for (int m = 0; m < 8; ++m) {
    const int rowbase = wr * 128 + m * 16 + lh * 4;
    int gr[4];
    float rmn[4], rmx[4];
#pragma unroll
    for (int r = 0; r < 4; ++r) {
      gr[r] = sgr[rowbase + r];
      rmn[r] = 3.0e38f; rmx[r] = -3.0e38f;
    }
#pragma unroll
    for (int n = 0; n < 4; ++n) {
      const int jj = j0 + wc * 64 + n * 16 + lr;
#pragma unroll
      for (int r = 0; r < 4; ++r) {
        float s = acc[m][n][r];
        int ii = i0 + rowbase + r;
        if (offdiag || (ii > jj)) {
          if (gr[r] == gj[n]) {
            rmn[r] = fminf(rmn[r], s);
          } else {
            rmx[r] = fmaxf(rmx[r], s);
            cmax[n] = fmaxf(cmax[n], s);
          }
        }
      }
    }
    // reduce across the 16 j-lanes
#pragma unroll
    for (int s = 1; s <= 8; s <<= 1)
#pragma unroll
      for (int r = 0; r < 4; ++r) {
        rmn[r] = fminf(rmn[r], __shfl_xor(rmn[r], s, 64));
        rmx[r] = fmaxf(rmx[r], __shfl_xor(rmx[r], s, 64));
      }
    if (lr == 0) {
#pragma unroll
      for (int r = 0; r < 4; ++r) {
        if (rmn[r] < 1.0e38f) atomicMin(&lgmin[gr[r]], enc_f32(rmn[r]));
        if (rmx[r] > -1.0e38f) atomicMax(&lgmax[gr[r]], enc_f32(rmx[r]));
      }
    }
  }
  // column maxes: reduce across the 4 i-lane-groups
#pragma unroll
  for (int s = 16; s <= 32; s <<= 1)
#pragma unroll
    for (int n = 0; n < 4; ++n)
      cmax[n] = fmaxf(cmax[n], __shfl_xor(cmax[n], s, 64));
  if (lh == 0) {
#pragma unroll
    for (int n = 0; n < 4; ++n)
      if (cmax[n] > -1.0e38f) atomicMax(&lgmax[gj[n]], enc_f32(cmax[n]));
  }
  __syncthreads();

  if (tid < NUMG) {
    uint32_t mn = lgmin[tid], mx = lgmax[tid];
    if (mn != 0xFFFFFFFFu) atomicMin(&gmin[tid], mn);
    if (mx != 0u) atomicMax(&gmax[tid], mx);
  }
}

// ---------------- finalize ----------------
__global__ void finalize_k(const uint32_t* __restrict__ gmin,
                           const uint32_t* __restrict__ gmax,
                           const int* __restrict__ counts,
                           float* __restrict__ out) {
  __shared__ float s_num[256];
  __shared__ float s_den[256];
  int t = threadIdx.x;
  float per = 0.f, ne = 0.f;
  if (counts[t] > 0) {
    ne = 1.f;
    float mn = (gmin[t] == 0xFFFFFFFFu) ? 1.0e9f : dec_f32(gmin[t]);
    float mx = (gmax[t] == 0u) ? -1.0e9f : dec_f32(gmax[t]);
    per = fmaxf(0.0f, mx - mn + MARGIN_F);
  }
  s_num[t] = per;
  s_den[t] = ne;
  __syncthreads();
  for (int s = 128; s > 0; s >>= 1) {
    if (t < s) { s_num[t] += s_num[t + s]; s_den[t] += s_den[t + s]; }
    __syncthreads();
  }
  if (t == 0) out[0] = s_num[0] / s_den[0];
}

extern "C" void kernel_launch(void* const* d_in, const int* in_sizes, int n_in,
                              void* d_out, int out_size, void* d_ws, size_t ws_size,
                              hipStream_t stream) {
  const float* x   = (const float*)d_in[0];
  const int* pidx  = (const int*)d_in[1];
  float* out       = (float*)d_out;

  char* ws = (char*)d_ws;
  unsigned short* xb = (unsigned short*)ws;
  size_t off = (size_t)KROWS * DDIM * 2;
  int* gids      = (int*)(ws + off); off += (size_t)KROWS * 4;
  int* counts    = (int*)(ws + off); off += NUMG * 4;
  uint32_t* gmin = (uint32_t*)(ws + off); off += NUMG * 4;
  uint32_t* gmax = (uint32_t*)(ws + off); off += NUMG * 4;

  hipLaunchKernelGGL(init_k, dim3(1), dim3(NUMG), 0, stream, gmin, gmax, counts);
  hipLaunchKernelGGL(extract_k, dim3(KROWS / 256), dim3(256), 0, stream,
                     pidx, gids, counts);
  hipLaunchKernelGGL(convert_k, dim3((KROWS * DDIM / 8) / 256), dim3(256), 0, stream,
                     x, xb);
  hipLaunchKernelGGL(gram_margin_k, dim3(NTILES * (NTILES + 1) / 2), dim3(512), 0,
                     stream, xb, gids, gmin, gmax);
  hipLaunchKernelGGL(finalize_k, dim3(1), dim3(NUMG), 0, stream,
                     gmin, gmax, counts, out);
}

// Round 4
// 143.090 us; speedup vs baseline: 1.0459x; 1.0184x over previous
//
#include <hip/hip_runtime.h>
#include <stdint.h>

#define KROWS 8192
#define DDIM  768
#define NUMG  256
#define BM    256
#define BK    64
#define NT    (DDIM / BK)     // 12 K-tiles
#define NTILES (KROWS / BM)   // 32 row/col tiles
#define TOTTILES (NTILES * (NTILES + 1) / 2)  // 528
#define GRID  512
#define MARGIN_F 0.1f

typedef short bf16x8 __attribute__((ext_vector_type(8)));
typedef float f32x4 __attribute__((ext_vector_type(4)));
typedef unsigned short u16x8 __attribute__((ext_vector_type(8)));

typedef __attribute__((address_space(3))) unsigned char lds_byte;
typedef __attribute__((address_space(1))) const unsigned char glob_byte;

__device__ __forceinline__ uint32_t enc_f32(float f) {
  uint32_t b = __float_as_uint(f);
  return (b & 0x80000000u) ? ~b : (b | 0x80000000u);
}
__device__ __forceinline__ float dec_f32(uint32_t u) {
  uint32_t b = (u & 0x80000000u) ? (u & 0x7FFFFFFFu) : ~u;
  return __uint_as_float(b);
}
__device__ __forceinline__ unsigned short f2bf(float f) {
  uint32_t b = __float_as_uint(f);
  uint32_t r = (b + 0x7FFFu + ((b >> 16) & 1u)) >> 16;
  return (unsigned short)r;
}

// ---------------- init: group arrays ----------------
__global__ void init_k(uint32_t* __restrict__ gmin, uint32_t* __restrict__ gmax,
                       int* __restrict__ counts) {
  int t = threadIdx.x;
  gmin[t] = 0xFFFFFFFFu;
  gmax[t] = 0u;
  counts[t] = 0;
}

// ---------------- extract group ids + counts ----------------
__global__ void extract_k(const int* __restrict__ pidx, int* __restrict__ gids,
                          int* __restrict__ counts) {
  int t = blockIdx.x * blockDim.x + threadIdx.x;
  if (t < KROWS) {
    int g = pidx[2 * t + 1] & (NUMG - 1);
    gids[t] = g;
    atomicAdd(&counts[g], 1);
  }
}

// ---------------- f32 -> bf16 convert ----------------
__global__ void convert_k(const float* __restrict__ x, unsigned short* __restrict__ xb) {
  int t = blockIdx.x * blockDim.x + threadIdx.x;
  const float4* p = reinterpret_cast<const float4*>(x + 8 * (size_t)t);
  float4 a = p[0], b = p[1];
  u16x8 r;
  r[0] = f2bf(a.x); r[1] = f2bf(a.y); r[2] = f2bf(a.z); r[3] = f2bf(a.w);
  r[4] = f2bf(b.x); r[5] = f2bf(b.y); r[6] = f2bf(b.z); r[7] = f2bf(b.w);
  *reinterpret_cast<u16x8*>(xb + 8 * (size_t)t) = r;
}

#define LOAD_A(dst, M, KS) {                                                 \
  int row_ = wrbase + (M) * 16 + lr;                                         \
  int off_ = row_ * 128 + (((lh * 16) + (KS) * 64) ^ ((row_ & 7) << 4));     \
  dst = *reinterpret_cast<const bf16x8*>(bufA_c + off_); }

#define MFMA16(MB)                                                            \
  __builtin_amdgcn_s_setprio(1);                                              \
  _Pragma("unroll")                                                           \
  for (int n = 0; n < 4; ++n) {                                               \
    acc[MB][n]     = __builtin_amdgcn_mfma_f32_16x16x32_bf16(af00, bfr[n][0], acc[MB][n], 0, 0, 0);     \
    acc[MB][n]     = __builtin_amdgcn_mfma_f32_16x16x32_bf16(af01, bfr[n][1], acc[MB][n], 0, 0, 0);     \
    acc[MB+1][n]   = __builtin_amdgcn_mfma_f32_16x16x32_bf16(af10, bfr[n][0], acc[MB+1][n], 0, 0, 0);   \
    acc[MB+1][n]   = __builtin_amdgcn_mfma_f32_16x16x32_bf16(af11, bfr[n][1], acc[MB+1][n], 0, 0, 0);   \
  }                                                                           \
  __builtin_amdgcn_s_setprio(0);

// ---------------- main fused Gram + margin-reduce kernel ----------------
// 256x256 tile, BK=64, 8 waves (2Mx4N), per-wave 128x64.
// 8-phase schedule (m201 template): per K-tile 4 phases of
// {ds_read subtile -> s_barrier -> lgkmcnt(0) -> 16 MFMA -> s_barrier};
// phase 0 additionally loads B-frags (8 reads) and issues next tile's 8
// global_load_lds. Tile boundary: vmcnt(0) (loads are ~3.5 phases old).
__launch_bounds__(512, 2)
__global__ void gram_margin_k(const unsigned short* __restrict__ xb,
                              const int* __restrict__ gids,
                              uint32_t* __restrict__ gmin,
                              uint32_t* __restrict__ gmax) {
  __shared__ unsigned short sA[2][BM * BK];   // 2 x 32 KB
  __shared__ unsigned short sB[2][BM * BK];   // 2 x 32 KB
  __shared__ uint32_t lgmin[NUMG];
  __shared__ uint32_t lgmax[NUMG];
  __shared__ int sgr[BM];
  __shared__ int sgc[BM];

  const int tid  = threadIdx.x;
  const int lane = tid & 63;
  const int wid  = tid >> 6;            // 0..7
  const int wr   = wid >> 2, wc = wid & 3;
  const int lr   = lane & 15, lh = lane >> 4;
  const int wrbase = wr * 128;

  const int srow = tid >> 3;    // 0..63
  const int schunk = tid & 7;   // 16B chunk in 128B row

  for (int tile = blockIdx.x; tile < TOTTILES; tile += GRID) {
    // triangular decode (ib >= jb)
    int ib = (int)((sqrtf(8.0f * (float)tile + 1.0f) - 1.0f) * 0.5f);
    while ((ib + 1) * (ib + 2) / 2 <= tile) ++ib;
    while (ib * (ib + 1) / 2 > tile) --ib;
    int jb = tile - ib * (ib + 1) / 2;
    const int i0 = ib * BM, j0 = jb * BM;

    __syncthreads();  // previous tile's epilogue fully done before re-init
    if (tid < NUMG) {
      lgmin[tid] = 0xFFFFFFFFu; lgmax[tid] = 0u;
      sgr[tid] = gids[i0 + tid];
      sgc[tid] = gids[j0 + tid];
    }

    f32x4 acc[8][4];
    const f32x4 zz = {0.f, 0.f, 0.f, 0.f};
#pragma unroll
    for (int m = 0; m < 8; ++m)
#pragma unroll
      for (int n = 0; n < 4; ++n) acc[m][n] = zz;

    auto stage = [&](int buf, int kt) {
      const int k0 = kt * BK;
#pragma unroll
      for (int c = 0; c < 4; ++c) {
        int row = c * 64 + srow;
        int chunk = schunk ^ (row & 7);   // pre-swizzled global source
        const unsigned short* ga = xb + (size_t)(i0 + row) * DDIM + k0 + chunk * 8;
        const unsigned short* gb = xb + (size_t)(j0 + row) * DDIM + k0 + chunk * 8;
        unsigned short* la = sA[buf] + (size_t)row * 64 + schunk * 8;
        unsigned short* lb = sB[buf] + (size_t)row * 64 + schunk * 8;
        __builtin_amdgcn_global_load_lds((glob_byte*)ga, (lds_byte*)la, 16, 0, 0);
        __builtin_amdgcn_global_load_lds((glob_byte*)gb, (lds_byte*)lb, 16, 0, 0);
      }
    };

    // ---- prologue: stage tile 0, drain, sync ----
    stage(0, 0);
    asm volatile("s_waitcnt vmcnt(0)" ::: "memory");
    __builtin_amdgcn_sched_barrier(0);
    __builtin_amdgcn_s_barrier();

    for (int t = 0; t < NT; ++t) {
      const int cur = t & 1;
      const char* bufA_c = reinterpret_cast<const char*>(sA[cur]);
      const char* bufB_c = reinterpret_cast<const char*>(sB[cur]);
      __builtin_amdgcn_sched_barrier(0);  // keep reads below boundary barrier

      // ================= phase 0: B-frags + A m0,m1 + stage(t+1) ========
      bf16x8 bfr[4][2];
#pragma unroll
      for (int n = 0; n < 4; ++n) {
        int row = wc * 64 + n * 16 + lr;
#pragma unroll
        for (int ks = 0; ks < 2; ++ks) {
          int off = row * 128 + (((lh * 16) + ks * 64) ^ ((row & 7) << 4));
          bfr[n][ks] = *reinterpret_cast<const bf16x8*>(bufB_c + off);
        }
      }
      bf16x8 af00, af01, af10, af11;
      LOAD_A(af00, 0, 0); LOAD_A(af01, 0, 1);
      LOAD_A(af10, 1, 0); LOAD_A(af11, 1, 1);
      if (t + 1 < NT) stage(cur ^ 1, t + 1);
      __builtin_amdgcn_s_barrier();
      asm volatile("s_waitcnt lgkmcnt(0)" ::: "memory");
      __builtin_amdgcn_sched_barrier(0);
      MFMA16(0)
      __builtin_amdgcn_s_barrier();

      // ================= phase 1: A m2,m3 =================
      LOAD_A(af00, 2, 0); LOAD_A(af01, 2, 1);
      LOAD_A(af10, 3, 0); LOAD_A(af11, 3, 1);
      __builtin_amdgcn_s_barrier();
      asm volatile("s_waitcnt lgkmcnt(0)" ::: "memory");
      __builtin_amdgcn_sched_barrier(0);
      MFMA16(2)
      __builtin_amdgcn_s_barrier();

      // ================= phase 2: A m4,m5 =================
      LOAD_A(af00, 4, 0); LOAD_A(af01, 4, 1);
      LOAD_A(af10, 5, 0); LOAD_A(af11, 5, 1);
      __builtin_amdgcn_s_barrier();
      asm volatile("s_waitcnt lgkmcnt(0)" ::: "memory");
      __builtin_amdgcn_sched_barrier(0);
      MFMA16(4)
      __builtin_amdgcn_s_barrier();

      // ================= phase 3: A m6,m7 =================
      LOAD_A(af00, 6, 0); LOAD_A(af01, 6, 1);
      LOAD_A(af10, 7, 0); LOAD_A(af11, 7, 1);
      __builtin_amdgcn_s_barrier();
      asm volatile("s_waitcnt lgkmcnt(0)" ::: "memory");
      __builtin_amdgcn_sched_barrier(0);
      MFMA16(6)
      // ---- tile boundary: staged loads are ~3.5 phases old ----
      if (t + 1 < NT) {
        asm volatile("s_waitcnt vmcnt(0)" ::: "memory");
        __builtin_amdgcn_sched_barrier(0);
      }
      __builtin_amdgcn_s_barrier();
    }

    // ---------------- fused epilogue ----------------
    // C/D: col = lane&15, row = (lane>>4)*4 + reg
    int gj[4];
#pragma unroll
    for (int n = 0; n < 4; ++n) gj[n] = sgc[wc * 64 + n * 16 + lr];

    const bool offdiag = (ib != jb);
    float cmax[4];
#pragma unroll
    for (int n = 0; n < 4; ++n) cmax[n] = -3.0e38f;

#pragma unroll
    for (int m = 0; m < 8; ++m) {
      const int rowbase = wr * 128 + m * 16 + lh * 4;
      int gr[4];
      float rmn[4], rmx[4];
#pragma unroll
      for (int r = 0; r < 4; ++r) {
        gr[r] = sgr[rowbase + r];
        rmn[r] = 3.0e38f; rmx[r] = -3.0e38f;
      }
#pragma unroll
      for (int n = 0; n < 4; ++n) {
        const int jj = j0 + wc * 64 + n * 16 + lr;
#pragma unroll
        for (int r = 0; r < 4; ++r) {
          float s = acc[m][n][r];
          int ii = i0 + rowbase + r;
          if (offdiag || (ii > jj)) {
            if (gr[r] == gj[n]) {
              rmn[r] = fminf(rmn[r], s);
            } else {
              rmx[r] = fmaxf(rmx[r], s);
              cmax[n] = fmaxf(cmax[n], s);
            }
          }
        }
      }
#pragma unroll
      for (int s = 1; s <= 8; s <<= 1)
#pragma unroll
        for (int r = 0; r < 4; ++r) {
          rmn[r] = fminf(rmn[r], __shfl_xor(rmn[r], s, 64));
          rmx[r] = fmaxf(rmx[r], __shfl_xor(rmx[r], s, 64));
        }
      if (lr == 0) {
#pragma unroll
        for (int r = 0; r < 4; ++r) {
          if (rmn[r] < 1.0e38f) atomicMin(&lgmin[gr[r]], enc_f32(rmn[r]));
          if (rmx[r] > -1.0e38f) atomicMax(&lgmax[gr[r]], enc_f32(rmx[r]));
        }
      }
    }
#pragma unroll
    for (int s = 16; s <= 32; s <<= 1)
#pragma unroll
      for (int n = 0; n < 4; ++n)
        cmax[n] = fmaxf(cmax[n], __shfl_xor(cmax[n], s, 64));
    if (lh == 0) {
#pragma unroll
      for (int n = 0; n < 4; ++n)
        if (cmax[n] > -1.0e38f) atomicMax(&lgmax[gj[n]], enc_f32(cmax[n]));
    }
    __syncthreads();

    if (tid < NUMG) {
      uint32_t mn = lgmin[tid], mx = lgmax[tid];
      if (mn != 0xFFFFFFFFu) atomicMin(&gmin[tid], mn);
      if (mx != 0u) atomicMax(&gmax[tid], mx);
    }
  }
}

// ---------------- finalize ----------------
__global__ void finalize_k(const uint32_t* __restrict__ gmin,
                           const uint32_t* __restrict__ gmax,
                           const int* __restrict__ counts,
                           float* __restrict__ out) {
  __shared__ float s_num[256];
  __shared__ float s_den[256];
  int t = threadIdx.x;
  float per = 0.f, ne = 0.f;
  if (counts[t] > 0) {
    ne = 1.f;
    float mn = (gmin[t] == 0xFFFFFFFFu) ? 1.0e9f : dec_f32(gmin[t]);
    float mx = (gmax[t] == 0u) ? -1.0e9f : dec_f32(gmax[t]);
    per = fmaxf(0.0f, mx - mn + MARGIN_F);
  }
  s_num[t] = per;
  s_den[t] = ne;
  __syncthreads();
  for (int s = 128; s > 0; s >>= 1) {
    if (t < s) { s_num[t] += s_num[t + s]; s_den[t] += s_den[t + s]; }
    __syncthreads();
  }
  if (t == 0) out[0] = s_num[0] / s_den[0];
}

extern "C" void kernel_launch(void* const* d_in, const int* in_sizes, int n_in,
                              void* d_out, int out_size, void* d_ws, size_t ws_size,
                              hipStream_t stream) {
  const float* x   = (const float*)d_in[0];
  const int* pidx  = (const int*)d_in[1];
  float* out       = (float*)d_out;

  char* ws = (char*)d_ws;
  unsigned short* xb = (unsigned short*)ws;
  size_t off = (size_t)KROWS * DDIM * 2;
  int* gids      = (int*)(ws + off); off += (size_t)KROWS * 4;
  int* counts    = (int*)(ws + off); off += NUMG * 4;
  uint32_t* gmin = (uint32_t*)(ws + off); off += NUMG * 4;
  uint32_t* gmax = (uint32_t*)(ws + off); off += NUMG * 4;

  hipLaunchKernelGGL(init_k, dim3(1), dim3(NUMG), 0, stream, gmin, gmax, counts);
  hipLaunchKernelGGL(extract_k, dim3(KROWS / 256), dim3(256), 0, stream,
                     pidx, gids, counts);
  hipLaunchKernelGGL(convert_k, dim3((KROWS * DDIM / 8) / 256), dim3(256), 0, stream,
                     x, xb);
  hipLaunchKernelGGL(gram_margin_k, dim3(GRID), dim3(512), 0,
                     stream, xb, gids, gmin, gmax);
  hipLaunchKernelGGL(finalize_k, dim3(1), dim3(NUMG), 0, stream,
                     gmin, gmax, counts, out);
}

// Round 5
// 121.033 us; speedup vs baseline: 1.2365x; 1.1822x over previous
//
#include <hip/hip_runtime.h>
#include <stdint.h>

#define KROWS 8192
#define DDIM  768
#define NUMG  256
#define BM    128
#define BK    64
#define NT    (DDIM / BK)                 // 12 K-tiles
#define NTILES (KROWS / BM)               // 64
#define TOTT (NTILES * (NTILES + 1) / 2)  // 2080
#define MARGIN_F 0.1f

typedef short bf16x8 __attribute__((ext_vector_type(8)));
typedef float f32x4 __attribute__((ext_vector_type(4)));
typedef unsigned short u16x8 __attribute__((ext_vector_type(8)));

typedef __attribute__((address_space(3))) unsigned char lds_byte;
typedef __attribute__((address_space(1))) const unsigned char glob_byte;

__device__ __forceinline__ uint32_t enc_f32(float f) {
  uint32_t b = __float_as_uint(f);
  return (b & 0x80000000u) ? ~b : (b | 0x80000000u);
}
__device__ __forceinline__ float dec_f32(uint32_t u) {
  uint32_t b = (u & 0x80000000u) ? (u & 0x7FFFFFFFu) : ~u;
  return __uint_as_float(b);
}
__device__ __forceinline__ unsigned short f2bf(float f) {
  uint32_t b = __float_as_uint(f);
  uint32_t r = (b + 0x7FFFu + ((b >> 16) & 1u)) >> 16;
  return (unsigned short)r;
}

// ---------------- convert f32->bf16 (8/thread) + fused gid extract ----------
__global__ void convert_k(const float* __restrict__ x, unsigned short* __restrict__ xb,
                          const int* __restrict__ pidx, int* __restrict__ gids,
                          int* __restrict__ counts) {
  int t = blockIdx.x * blockDim.x + threadIdx.x;   // 98304 threads
  const float4* p = reinterpret_cast<const float4*>(x + 8 * (size_t)t);
  float4 a = p[0], b = p[1];
  u16x8 r;
  r[0] = f2bf(a.x); r[1] = f2bf(a.y); r[2] = f2bf(a.z); r[3] = f2bf(a.w);
  r[4] = f2bf(b.x); r[5] = f2bf(b.y); r[6] = f2bf(b.z); r[7] = f2bf(b.w);
  *reinterpret_cast<u16x8*>(xb + 8 * (size_t)t) = r;
  if (t < KROWS) {
    int g = pidx[2 * t + 1] & (NUMG - 1);
    gids[t] = g;
    atomicAdd(&counts[g], 1);
  }
}

// ---------------- main fused Gram + margin-reduce kernel ----------------
// r1 structure (single-buffer, 4 waves of 2x2, serial drain per K-tile) +
// supertile/XCD-chunked swizzle: 8x8-tile supertiles (A+B = 3MB < 4MB L2/XCD),
// each XCD gets a contiguous 260-bid chunk so its ~128 concurrent blocks
// span <=2 supertiles -> panel reads become XCD-L2 hits.
__launch_bounds__(256, 2)
__global__ void gram_margin_k(const unsigned short* __restrict__ xb,
                              const int* __restrict__ gids,
                              uint32_t* __restrict__ gmin,
                              uint32_t* __restrict__ gmax) {
  __shared__ unsigned short sA[BM * BK];
  __shared__ unsigned short sB[BM * BK];
  __shared__ uint32_t lgmin[NUMG];
  __shared__ uint32_t lgmax[NUMG];
  __shared__ int sgr[BM];
  __shared__ int sgc[BM];

  const int tid  = threadIdx.x;
  const int lane = tid & 63;
  const int wid  = tid >> 6;
  const int wr   = wid >> 1, wc = wid & 1;
  const int lr   = lane & 15, lh = lane >> 4;

  // ---- XCD-chunked supertile decode ----
  // idx: contiguous 260-range per XCD (2080 = 8*260, bijective)
  int phys = blockIdx.x;
  int idx  = (phys & 7) * (TOTT / 8) + (phys >> 3);
  int ib, jb;
  if (idx < 288) {                 // 8 diagonal supertiles, 36 tiles each
    int d = idx / 36, r = idx - d * 36;
    int i2 = (int)((sqrtf(8.0f * (float)r + 1.0f) - 1.0f) * 0.5f);
    while ((i2 + 1) * (i2 + 2) / 2 <= r) ++i2;
    while (i2 * (i2 + 1) / 2 > r) --i2;
    int j2 = r - i2 * (i2 + 1) / 2;
    ib = d * 8 + i2; jb = d * 8 + j2;
  } else {                         // 28 off-diagonal supertiles, 64 tiles each
    int o = (idx - 288) >> 6, t = (idx - 288) & 63;
    int si = (int)((sqrtf(8.0f * (float)o + 1.0f) - 1.0f) * 0.5f);
    while ((si + 1) * (si + 2) / 2 <= o) ++si;
    while (si * (si + 1) / 2 > o) --si;
    int sj = o - si * (si + 1) / 2;
    si += 1;                       // strictly-lower supertile: SI in 1..7
    ib = si * 8 + (t >> 3); jb = sj * 8 + (t & 7);
  }
  const int i0 = ib * BM, j0 = jb * BM;

  if (tid < NUMG) { lgmin[tid] = 0xFFFFFFFFu; lgmax[tid] = 0u; }
  if (tid < BM)   { sgr[tid] = gids[i0 + tid]; sgc[tid] = gids[j0 + tid]; }

  f32x4 acc[4][4];
  const f32x4 zz = {0.f, 0.f, 0.f, 0.f};
#pragma unroll
  for (int m = 0; m < 4; ++m)
#pragma unroll
    for (int n = 0; n < 4; ++n) acc[m][n] = zz;

  const int srow = tid >> 3;   // 0..31 (row within 32-row staging chunk)
  const int schunk = tid & 7;  // 16B chunk within 128B row

  for (int kt = 0; kt < NT; ++kt) {
    const int k0 = kt * BK;
#pragma unroll
    for (int c = 0; c < 4; ++c) {
      int row = c * 32 + srow;
      int chunk = schunk ^ (row & 7);  // pre-swizzle global source
      const unsigned short* ga = xb + (size_t)(i0 + row) * DDIM + k0 + chunk * 8;
      const unsigned short* gb = xb + (size_t)(j0 + row) * DDIM + k0 + chunk * 8;
      unsigned short* la = sA + c * 2048 + tid * 8;
      unsigned short* lb = sB + c * 2048 + tid * 8;
      __builtin_amdgcn_global_load_lds((glob_byte*)ga, (lds_byte*)la, 16, 0, 0);
      __builtin_amdgcn_global_load_lds((glob_byte*)gb, (lds_byte*)lb, 16, 0, 0);
    }
    __syncthreads();
#pragma unroll
    for (int ks = 0; ks < 2; ++ks) {
      bf16x8 af[4], bfr[4];
#pragma unroll
      for (int m = 0; m < 4; ++m) {
        int row = wr * 64 + m * 16 + lr;
        int byteoff = row * 128 + ((lh * 16 + ks * 64) ^ ((row & 7) << 4));
        af[m] = *reinterpret_cast<const bf16x8*>(
            reinterpret_cast<const char*>(sA) + byteoff);
      }
#pragma unroll
      for (int n = 0; n < 4; ++n) {
        int row = wc * 64 + n * 16 + lr;
        int byteoff = row * 128 + ((lh * 16 + ks * 64) ^ ((row & 7) << 4));
        bfr[n] = *reinterpret_cast<const bf16x8*>(
            reinterpret_cast<const char*>(sB) + byteoff);
      }
#pragma unroll
      for (int m = 0; m < 4; ++m)
#pragma unroll
        for (int n = 0; n < 4; ++n)
          acc[m][n] = __builtin_amdgcn_mfma_f32_16x16x32_bf16(af[m], bfr[n],
                                                              acc[m][n], 0, 0, 0);
    }
    __syncthreads();
  }

  // ---------------- fused epilogue ----------------
  // C/D layout: col = lane&15, row = (lane>>4)*4 + reg  [m89-verified]
  int gi[4][4];
#pragma unroll
  for (int m = 0; m < 4; ++m)
#pragma unroll
    for (int r = 0; r < 4; ++r) gi[m][r] = sgr[wr * 64 + m * 16 + lh * 4 + r];
  int gj[4];
#pragma unroll
  for (int n = 0; n < 4; ++n) gj[n] = sgc[wc * 64 + n * 16 + lr];

  float rmin[4][4], rmax[4][4], cmax[4];
#pragma unroll
  for (int m = 0; m < 4; ++m)
#pragma unroll
    for (int r = 0; r < 4; ++r) { rmin[m][r] = 3.0e38f; rmax[m][r] = -3.0e38f; }
#pragma unroll
  for (int n = 0; n < 4; ++n) cmax[n] = -3.0e38f;

  const bool offdiag = (ib != jb);
#pragma unroll
  for (int m = 0; m < 4; ++m) {
#pragma unroll
    for (int r = 0; r < 4; ++r) {
      int ii = i0 + wr * 64 + m * 16 + lh * 4 + r;
#pragma unroll
      for (int n = 0; n < 4; ++n) {
        int jj = j0 + wc * 64 + n * 16 + lr;
        float s = acc[m][n][r];
        if (offdiag || (ii > jj)) {
          if (gi[m][r] == gj[n]) {
            rmin[m][r] = fminf(rmin[m][r], s);
          } else {
            rmax[m][r] = fmaxf(rmax[m][r], s);
            cmax[n] = fmaxf(cmax[n], s);
          }
        }
      }
    }
  }

  // reduce rows across the 16 j-lanes (xor 1,2,4,8)
#pragma unroll
  for (int s = 1; s <= 8; s <<= 1) {
#pragma unroll
    for (int m = 0; m < 4; ++m)
#pragma unroll
      for (int r = 0; r < 4; ++r) {
        rmin[m][r] = fminf(rmin[m][r], __shfl_xor(rmin[m][r], s, 64));
        rmax[m][r] = fmaxf(rmax[m][r], __shfl_xor(rmax[m][r], s, 64));
      }
  }
  // reduce cols across the 4 i-lane-groups (xor 16, 32)
#pragma unroll
  for (int s = 16; s <= 32; s <<= 1)
#pragma unroll
    for (int n = 0; n < 4; ++n)
      cmax[n] = fmaxf(cmax[n], __shfl_xor(cmax[n], s, 64));

  if (lr == 0) {
#pragma unroll
    for (int m = 0; m < 4; ++m)
#pragma unroll
      for (int r = 0; r < 4; ++r) {
        if (rmin[m][r] < 1.0e38f) atomicMin(&lgmin[gi[m][r]], enc_f32(rmin[m][r]));
        if (rmax[m][r] > -1.0e38f) atomicMax(&lgmax[gi[m][r]], enc_f32(rmax[m][r]));
      }
  }
  if (lh == 0) {
#pragma unroll
    for (int n = 0; n < 4; ++n)
      if (cmax[n] > -1.0e38f) atomicMax(&lgmax[gj[n]], enc_f32(cmax[n]));
  }
  __syncthreads();

  // merge block-local group arrays to global (tid covers all 256 groups)
  {
    uint32_t mn = lgmin[tid], mx = lgmax[tid];
    if (mn != 0xFFFFFFFFu) atomicMin(&gmin[tid], mn);
    if (mx != 0u) atomicMax(&gmax[tid], mx);
  }
}

// ---------------- finalize: per-group margin + mean ----------------
__global__ void finalize_k(const uint32_t* __restrict__ gmin,
                           const uint32_t* __restrict__ gmax,
                           const int* __restrict__ counts,
                           float* __restrict__ out) {
  __shared__ float s_num[256];
  __shared__ float s_den[256];
  int t = threadIdx.x;
  float per = 0.f, ne = 0.f;
  if (counts[t] > 0) {
    ne = 1.f;
    float mn = (gmin[t] == 0xFFFFFFFFu) ? 1.0e9f : dec_f32(gmin[t]);
    float mx = (gmax[t] == 0u) ? -1.0e9f : dec_f32(gmax[t]);
    per = fmaxf(0.0f, mx - mn + MARGIN_F);
  }
  s_num[t] = per;
  s_den[t] = ne;
  __syncthreads();
  for (int s = 128; s > 0; s >>= 1) {
    if (t < s) { s_num[t] += s_num[t + s]; s_den[t] += s_den[t + s]; }
    __syncthreads();
  }
  if (t == 0) out[0] = s_num[0] / s_den[0];
}

extern "C" void kernel_launch(void* const* d_in, const int* in_sizes, int n_in,
                              void* d_out, int out_size, void* d_ws, size_t ws_size,
                              hipStream_t stream) {
  const float* x   = (const float*)d_in[0];
  const int* pidx  = (const int*)d_in[1];
  float* out       = (float*)d_out;

  char* ws = (char*)d_ws;
  unsigned short* xb = (unsigned short*)ws;
  size_t off = (size_t)KROWS * DDIM * 2;          // 12,582,912 B
  int* gids      = (int*)(ws + off); off += (size_t)KROWS * 4;
  uint32_t* gmin = (uint32_t*)(ws + off); off += NUMG * 4;
  uint32_t* gmax = (uint32_t*)(ws + off); off += NUMG * 4;   // gmax, counts adjacent
  int* counts    = (int*)(ws + off); off += NUMG * 4;

  // init: gmin = 0xFFFFFFFF (encodes +max), gmax = 0 (encodes -max), counts = 0
  hipMemsetAsync(gmin, 0xFF, NUMG * 4, stream);
  hipMemsetAsync(gmax, 0x00, NUMG * 8, stream);   // covers gmax + counts

  hipLaunchKernelGGL(convert_k, dim3((KROWS * DDIM / 8) / 256), dim3(256), 0, stream,
                     x, xb, pidx, gids, counts);
  hipLaunchKernelGGL(gram_margin_k, dim3(TOTT), dim3(256), 0,
                     stream, xb, gids, gmin, gmax);
  hipLaunchKernelGGL(finalize_k, dim3(1), dim3(NUMG), 0, stream,
                     gmin, gmax, counts, out);
}